// Round 11
// baseline (81.373 us; speedup 1.0000x reference)
//
#include <hip/hip_runtime.h>
#include <hip/hip_bf16.h>

typedef float f32x4 __attribute__((ext_vector_type(4)));
typedef _Float16 f16x2 __attribute__((ext_vector_type(2)));
typedef _Float16 f16x8 __attribute__((ext_vector_type(8)));

#define CC   64
#define HID  256
#define NOUT 64
#define HOUT 384
#define MAXCELL 16                // 16x16 tile: <=4 cell-rows x 4 cell-cols
#define CELLB 544                 // 512 data + 32 pad
#define UVB  (MAXCELL * CELLB)    // 8704
#define W2B  (UVB + 1024)         // 9728
#define SMEMB (W2B + 32768)       // 42496 B -> 3 blocks/CU (512 thr = 24 waves/CU)

// ---- k_prep: w2 -> W2F frags, w1[0:64] -> W1F frags, w1[64:66] -> UVH f16
__global__ __launch_bounds__(256) void k_prep(const float* __restrict__ w1,
                                              const float* __restrict__ w2,
                                              _Float16* __restrict__ W2F,
                                              _Float16* __restrict__ W1F,
                                              _Float16* __restrict__ UVH) {
    int idx = blockIdx.x * 256 + threadIdx.x;
    if (idx < 16384) {
        int f = idx, e = f & 7, l = (f >> 3) & 63, grp = f >> 9;
        int ks = grp >> 2, ng = grp & 3;
        int k = ks * 32 + ((l >> 4) << 3) + e;
        int n = (ng << 4) + (l & 15);
        W2F[f] = (_Float16)w2[k * NOUT + n];
    } else if (idx < 32768) {
        int f = idx - 16384, e = f & 7, l = (f >> 3) & 63, grp = f >> 9;
        int ks = grp >> 4, ng = grp & 15;
        int k = ks * 32 + ((l >> 4) << 3) + e;
        int n = (ng << 4) + (l & 15);
        W1F[f] = (_Float16)w1[k * HID + n];
    } else if (idx < 32768 + 512) {
        int f = idx - 32768;
        UVH[f] = (_Float16)w1[(CC + (f >> 8)) * HID + (f & 255)];
    }
}

// ---- k_gfeat (MFMA): G[cell][n] = b1[n] + sum_c res_f16[cell][c] * w1_f16[c][n]
__global__ __launch_bounds__(256) void k_gfeat(const float* __restrict__ res,
                                               const _Float16* __restrict__ W1F,
                                               const float* __restrict__ b1,
                                               _Float16* __restrict__ G) {
    const int cell0 = blockIdx.x * 32;
    const int b = cell0 >> 12, iyix0 = cell0 & 4095;
    const int tid = threadIdx.x;
    __shared__ _Float16 lds_a[32][72];
    __shared__ _Float16 lds_d[32][264];
    {
        int c = tid >> 2, cs = (tid & 3) * 8;
        const float* src = res + (((b * CC + c) << 12) + iyix0 + cs);
        f32x4 r0 = *(const f32x4*)src;
        f32x4 r1 = *(const f32x4*)(src + 4);
#pragma unroll
        for (int e = 0; e < 4; ++e) lds_a[cs + e][c] = (_Float16)r0[e];
#pragma unroll
        for (int e = 0; e < 4; ++e) lds_a[cs + 4 + e][c] = (_Float16)r1[e];
    }
    __syncthreads();
    const int wv = tid >> 6, l = tid & 63, lhi = l >> 4, dj = l & 15;
    const int crow = (wv & 1) * 16;
    const int nh = (wv >> 1) * 8;
    f32x4 acc[8];
#pragma unroll
    for (int q = 0; q < 8; ++q) {
        float bb = b1[(nh + q) * 16 + dj];
        acc[q] = (f32x4){bb, bb, bb, bb};
    }
#pragma unroll
    for (int ks = 0; ks < 2; ++ks) {
        f16x8 afr = *(const f16x8*)&lds_a[crow + dj][ks * 32 + lhi * 8];
#pragma unroll
        for (int q = 0; q < 8; ++q) {
            f16x8 bfr = *(const f16x8*)(W1F + (((ks * 16 + nh + q) * 64 + l) << 3));
            acc[q] = __builtin_amdgcn_mfma_f32_16x16x32_f16(afr, bfr, acc[q], 0, 0, 0);
        }
    }
#pragma unroll
    for (int q = 0; q < 8; ++q) {
        int n = (nh + q) * 16 + dj;
#pragma unroll
        for (int r = 0; r < 4; ++r)
            lds_d[crow + lhi * 4 + r][n] = (_Float16)acc[q][r];
    }
    __syncthreads();
    {
        int cell = tid >> 3, ch = (tid & 7) * 32;
        _Float16* dst = G + (((size_t)(cell0 + cell)) << 8) + ch;
#pragma unroll
        for (int r = 0; r < 4; ++r)
            *(f32x4*)(dst + r * 8) = *(const f32x4*)&lds_d[cell][ch + r * 8];
    }
}

// ---- main: block = 8 waves (512 thr), tile = 16 rows x 16 cols; wave = 2
// adjacent rows sharing one cell-row (strip A even => never splits). ks-outer:
// uv + w2 read once per ks for 32 px; W2F staged once per 512-thread block.
__global__ __launch_bounds__(512, 6) void k_main(const _Float16* __restrict__ G,
                                                 const _Float16* __restrict__ W2F,
                                                 const _Float16* __restrict__ UVH,
                                                 const float* __restrict__ b2,
                                                 float* __restrict__ out) {
    const int jt = blockIdx.x;        // 0..23
    const int it = blockIdx.y;        // 0..23
    const int b  = blockIdx.z;        // 0..1
    const int tid = threadIdx.x;
    const int wv = tid >> 6, l = tid & 63;
    const int lhi = l >> 4, dj = l & 15;
    const int i0 = it * 16, j0 = jt * 16;

    __shared__ char smem[SMEMB];

    // ---- integer staged-cell bounds
    const int r0 = i0 / 6;
    const int i15 = i0 + 15, ci15 = i15 / 6;
    const int r1 = min(ci15 + ((i15 - 6 * ci15) == 5 ? 1 : 0), 63);
    const int c0 = j0 / 6;
    const int j15 = j0 + 15, cj15 = j15 / 6;
    const int c1 = min(cj15 + ((j15 - 6 * cj15) == 5 ? 1 : 0), 63);
    const int ncc = c1 - c0 + 1;              // 3 or 4
    const int ncell = (r1 - r0 + 1) * ncc;    // <= 16

    // ---- stage: cells (one b128 per thread), uv, W2F (4 b128 per thread)
    if (tid < (ncell << 5)) {
        int cl = tid >> 5, c16 = tid & 31;
        int cr = (ncc == 4) ? (cl >> 2) : ((cl * 11) >> 5);
        int cc = cl - cr * ncc;
        const _Float16* src = G + (((size_t)((b << 12) + ((r0 + cr) << 6) + (c0 + cc))) << 8) + (c16 << 3);
        *(f32x4*)(smem + cl * CELLB + (c16 << 4)) = *(const f32x4*)src;
    }
    if (tid < 64)
        *(f32x4*)(smem + UVB + (tid << 4)) = *(const f32x4*)(UVH + (tid << 3));
    {
        const f32x4* w2g = (const f32x4*)W2F;
#pragma unroll
        for (int t = 0; t < 4; ++t)
            *(f32x4*)(smem + W2B + ((t * 512 + tid) << 4)) = w2g[t * 512 + tid];
    }
    float bbv[4];
#pragma unroll
    for (int ng = 0; ng < 4; ++ng) bbv[ng] = b2[(ng << 4) + dj];
    __syncthreads();

    // ---- x setup (per lane)
    const int j = j0 + dj;
    const int cj = j / 6, pj = j - 6 * cj;
    const bool xs = (pj == 5) && (cj < 63);
    const float rx0 = (float)(2 * pj - 5) * (1.f / 6.f);
    const float rx1 = xs ? rx0 - 2.f : rx0;

    // ---- y setup: strip A = row ia (even => pia in {0,2,4}), strip B = ia+1
    const int ia = i0 + (wv << 1);
    const int cia = ia / 6, pia = ia - 6 * cia;
    const float ryA = (float)(2 * pia - 5) * (1.f / 6.f);
    const float ryB = ryA + (1.f / 3.f);
    const bool ysB = (pia == 4) && (cia < 63);
    const float ryB1 = ysB ? ryB - 2.f : ryB;

    // strip A weights (ys=false folded)
    const float aA0 = fabsf(ryA * rx0) + 1e-9f;
    const float aA1 = fabsf(ryA * rx1) + 1e-9f;
    const float invA = 1.f / (aA0 + aA1);
    const float W00A = xs ? aA1 * invA : 1.f;
    const float W01A = xs ? aA0 * invA : 0.f;
    // strip B weights (general, diagonal swap)
    const float aB0 = fabsf(ryB * rx0) + 1e-9f;
    const float aB1 = fabsf(ryB * rx1) + 1e-9f;
    const float aB2 = fabsf(ryB1 * rx0) + 1e-9f;
    const float aB3 = fabsf(ryB1 * rx1) + 1e-9f;
    const float invB = 1.f / (aB0 + aB1 + aB2 + aB3);
    float W00B = aB3, W01B = 0.f, W10B = 0.f, W11B = 0.f;
    if (xs) W01B += aB2; else W00B += aB2;
    if (ysB) W10B += aB1; else W00B += aB1;
    if (ysB && xs) W11B += aB0;
    else if (ysB)  W10B += aB0;
    else if (xs)   W01B += aB0;
    else           W00B += aB0;
    W00B *= invB; W01B *= invB; W10B *= invB; W11B *= invB;

#define DUP2(x) (f16x2){(_Float16)(x), (_Float16)(x)}
    const f16x2 ryAh = DUP2(ryA), ryB1h = DUP2(ryB1);
    const f16x2 rx0h = DUP2(rx0), rx1h = DUP2(rx1);
    const f16x2 thirdh = DUP2(1.f / 3.f);
    const f16x2 W00Ah = DUP2(W00A), W01Ah = DUP2(W01A);
    const f16x2 W00Bh = DUP2(W00B), W01Bh = DUP2(W01B);
    const f16x2 W10h = DUP2(W10B), W11h = DUP2(W11B);
    const f16x2 zeroh = DUP2(0.f);

    const int lo16 = lhi << 4;
    const int rA = cia - r0;
    const int cm = cj - c0, cp = cm + (xs ? 1 : 0);
    const char* cell00 = smem + (rA * ncc + cm) * CELLB + lo16;
    const char* cell01 = smem + (rA * ncc + cp) * CELLB + lo16;
    const char* cell10 = cell00 + ncc * CELLB;
    const char* cell11 = cell01 + ncc * CELLB;
    const char* uvp = smem + UVB + lo16;
    const f16x8* w2l = (const f16x8*)(smem + W2B) + l;

    f32x4 acc[2][4];
#pragma unroll
    for (int s = 0; s < 2; ++s)
#pragma unroll
        for (int ng = 0; ng < 4; ++ng) acc[s][ng] = (f32x4){0.f, 0.f, 0.f, 0.f};

#pragma unroll
    for (int ks = 0; ks < 8; ++ks) {
        const int ko = ks * 64;
        f16x8 uraw = *(const f16x8*)(uvp + ko);
        f16x8 vraw = *(const f16x8*)(uvp + 512 + ko);
        const f16x2* uu = (const f16x2*)&uraw;
        const f16x2* vv = (const f16x2*)&vraw;
        f16x8 bfr[4];
#pragma unroll
        for (int ng = 0; ng < 4; ++ng) bfr[ng] = w2l[(ks * 4 + ng) * 64];
        f16x8 gv00 = *(const f16x8*)(cell00 + ko);
        f16x8 gv01 = *(const f16x8*)(cell01 + ko);
        const f16x2* g00 = (const f16x2*)&gv00;
        const f16x2* g01 = (const f16x2*)&gv01;
        f16x2 hA[4], hB[4];
#pragma unroll
        for (int e = 0; e < 4; ++e) {
            f16x2 t00 = g00[e] + ryAh * uu[e] + rx0h * vv[e];
            f16x2 t01 = g01[e] + ryAh * uu[e] + rx1h * vv[e];
            f16x2 t00B = t00 + thirdh * uu[e];      // strip B shares cells, ry+1/3
            f16x2 t01B = t01 + thirdh * uu[e];
            t00 = __builtin_elementwise_max(t00, zeroh);
            t01 = __builtin_elementwise_max(t01, zeroh);
            t00B = __builtin_elementwise_max(t00B, zeroh);
            t01B = __builtin_elementwise_max(t01B, zeroh);
            hA[e] = W00Ah * t00 + W01Ah * t01;
            hB[e] = W00Bh * t00B + W01Bh * t01B;
        }
        if (ysB) {                                   // wave-uniform
            f16x8 gv10 = *(const f16x8*)(cell10 + ko);
            f16x8 gv11 = *(const f16x8*)(cell11 + ko);
            const f16x2* g10 = (const f16x2*)&gv10;
            const f16x2* g11 = (const f16x2*)&gv11;
#pragma unroll
            for (int e = 0; e < 4; ++e) {
                f16x2 t10 = g10[e] + ryB1h * uu[e] + rx0h * vv[e];
                f16x2 t11 = g11[e] + ryB1h * uu[e] + rx1h * vv[e];
                hB[e] += W10h * __builtin_elementwise_max(t10, zeroh);
                hB[e] += W11h * __builtin_elementwise_max(t11, zeroh);
            }
        }
        f16x8 afA, afB;
#pragma unroll
        for (int e = 0; e < 4; ++e) {
            afA[2 * e] = hA[e][0]; afA[2 * e + 1] = hA[e][1];
            afB[2 * e] = hB[e][0]; afB[2 * e + 1] = hB[e][1];
        }
#pragma unroll
        for (int ng = 0; ng < 4; ++ng)
            acc[0][ng] = __builtin_amdgcn_mfma_f32_16x16x32_f16(afA, bfr[ng], acc[0][ng], 0, 0, 0);
#pragma unroll
        for (int ng = 0; ng < 4; ++ng)
            acc[1][ng] = __builtin_amdgcn_mfma_f32_16x16x32_f16(afB, bfr[ng], acc[1][ng], 0, 0, 0);
    }

    // ---- epilogue: direct stores (D row = px col j0+lhi*4+r, D col = channel)
#pragma unroll
    for (int s = 0; s < 2; ++s) {
        const int irow = ia + s;
#pragma unroll
        for (int ng = 0; ng < 4; ++ng) {
            const int o = (ng << 4) + dj;
            float* op = out + (((size_t)b * NOUT + o) * HOUT + irow) * HOUT + j0 + (lhi << 2);
#pragma unroll
            for (int r = 0; r < 4; ++r)
                op[r] = acc[s][ng][r] + bbv[ng];
        }
    }
}

extern "C" void kernel_launch(void* const* d_in, const int* in_sizes, int n_in,
                              void* d_out, int out_size, void* d_ws, size_t ws_size,
                              hipStream_t stream) {
    const float* res = (const float*)d_in[0];
    const float* w1  = (const float*)d_in[1];
    const float* b1  = (const float*)d_in[2];
    const float* w2  = (const float*)d_in[3];
    const float* b2  = (const float*)d_in[4];
    float* out = (float*)d_out;

    char* ws = (char*)d_ws;
    _Float16* G   = (_Float16*)ws;                              // 4 MB
    _Float16* W2F = (_Float16*)(ws + (size_t)(8u << 20));       // 32 KB
    _Float16* W1F = (_Float16*)(ws + (size_t)(8u << 20) + 65536);
    _Float16* UVH = (_Float16*)(ws + (size_t)(8u << 20) + 131072);

    k_prep<<<130, 256, 0, stream>>>(w1, w2, W2F, W1F, UVH);
    k_gfeat<<<256, 256, 0, stream>>>(res, W1F, b1, G);
    k_main<<<dim3(24, 24, 2), 512, 0, stream>>>(G, W2F, UVH, b2, out);
}

// Round 12
// 40.630 us; speedup vs baseline: 2.0028x; 2.0028x over previous
//
#include <hip/hip_runtime.h>
#include <hip/hip_bf16.h>

typedef float f32x4 __attribute__((ext_vector_type(4)));
typedef _Float16 f16x2 __attribute__((ext_vector_type(2)));
typedef _Float16 f16x8 __attribute__((ext_vector_type(8)));

#define CC   64
#define HID  256
#define NOUT 64
#define HOUT 384
#define MAXCELL 16                // 16x16 tile: <=4 cell-rows x 4 cell-cols
#define CELLB 544                 // 512 data + 32 pad
#define UVB  (MAXCELL * CELLB)    // 8704
#define W2B  (UVB + 1024)         // 9728
#define SMEMB (W2B + 32768)       // 42496 B -> 3 blocks/CU (512 thr = 24 waves/CU)

// ---- k_prep: w2 -> W2F frags, w1[0:64] -> W1F frags, w1[64:66] -> UVH f16
__global__ __launch_bounds__(256) void k_prep(const float* __restrict__ w1,
                                              const float* __restrict__ w2,
                                              _Float16* __restrict__ W2F,
                                              _Float16* __restrict__ W1F,
                                              _Float16* __restrict__ UVH) {
    int idx = blockIdx.x * 256 + threadIdx.x;
    if (idx < 16384) {
        int f = idx, e = f & 7, l = (f >> 3) & 63, grp = f >> 9;
        int ks = grp >> 2, ng = grp & 3;
        int k = ks * 32 + ((l >> 4) << 3) + e;
        int n = (ng << 4) + (l & 15);
        W2F[f] = (_Float16)w2[k * NOUT + n];
    } else if (idx < 32768) {
        int f = idx - 16384, e = f & 7, l = (f >> 3) & 63, grp = f >> 9;
        int ks = grp >> 4, ng = grp & 15;
        int k = ks * 32 + ((l >> 4) << 3) + e;
        int n = (ng << 4) + (l & 15);
        W1F[f] = (_Float16)w1[k * HID + n];
    } else if (idx < 32768 + 512) {
        int f = idx - 32768;
        UVH[f] = (_Float16)w1[(CC + (f >> 8)) * HID + (f & 255)];
    }
}

// ---- k_gfeat (MFMA): G[cell][n] = b1[n] + sum_c res_f16[cell][c] * w1_f16[c][n]
__global__ __launch_bounds__(256) void k_gfeat(const float* __restrict__ res,
                                               const _Float16* __restrict__ W1F,
                                               const float* __restrict__ b1,
                                               _Float16* __restrict__ G) {
    const int cell0 = blockIdx.x * 32;
    const int b = cell0 >> 12, iyix0 = cell0 & 4095;
    const int tid = threadIdx.x;
    __shared__ _Float16 lds_a[32][72];
    __shared__ _Float16 lds_d[32][264];
    {
        int c = tid >> 2, cs = (tid & 3) * 8;
        const float* src = res + (((b * CC + c) << 12) + iyix0 + cs);
        f32x4 r0 = *(const f32x4*)src;
        f32x4 r1 = *(const f32x4*)(src + 4);
#pragma unroll
        for (int e = 0; e < 4; ++e) lds_a[cs + e][c] = (_Float16)r0[e];
#pragma unroll
        for (int e = 0; e < 4; ++e) lds_a[cs + 4 + e][c] = (_Float16)r1[e];
    }
    __syncthreads();
    const int wv = tid >> 6, l = tid & 63, lhi = l >> 4, dj = l & 15;
    const int crow = (wv & 1) * 16;
    const int nh = (wv >> 1) * 8;
    f32x4 acc[8];
#pragma unroll
    for (int q = 0; q < 8; ++q) {
        float bb = b1[(nh + q) * 16 + dj];
        acc[q] = (f32x4){bb, bb, bb, bb};
    }
#pragma unroll
    for (int ks = 0; ks < 2; ++ks) {
        f16x8 afr = *(const f16x8*)&lds_a[crow + dj][ks * 32 + lhi * 8];
#pragma unroll
        for (int q = 0; q < 8; ++q) {
            f16x8 bfr = *(const f16x8*)(W1F + (((ks * 16 + nh + q) * 64 + l) << 3));
            acc[q] = __builtin_amdgcn_mfma_f32_16x16x32_f16(afr, bfr, acc[q], 0, 0, 0);
        }
    }
#pragma unroll
    for (int q = 0; q < 8; ++q) {
        int n = (nh + q) * 16 + dj;
#pragma unroll
        for (int r = 0; r < 4; ++r)
            lds_d[crow + lhi * 4 + r][n] = (_Float16)acc[q][r];
    }
    __syncthreads();
    {
        int cell = tid >> 3, ch = (tid & 7) * 32;
        _Float16* dst = G + (((size_t)(cell0 + cell)) << 8) + ch;
#pragma unroll
        for (int r = 0; r < 4; ++r)
            *(f32x4*)(dst + r * 8) = *(const f32x4*)&lds_d[cell][ch + r * 8];
    }
}

// ---- main: block = 8 waves (512 thr), tile = 16 rows x 16 cols; wave = 2
// adjacent rows sharing one cell-row (strip A even => never splits). ks-outer:
// uv + w2 read once per ks for 32 px; W2F staged once per 512-thread block.
// NOTE: launch_bounds min-waves arg = 2 (NOT 6): at 8 waves/block the arg is
// effectively multiplied by waves/block in the VGPR-cap calc; 6 forced a
// 40-VGPR spill-storm (R11: +131 MB scratch writes).
__global__ __launch_bounds__(512, 2) void k_main(const _Float16* __restrict__ G,
                                                 const _Float16* __restrict__ W2F,
                                                 const _Float16* __restrict__ UVH,
                                                 const float* __restrict__ b2,
                                                 float* __restrict__ out) {
    const int jt = blockIdx.x;        // 0..23
    const int it = blockIdx.y;        // 0..23
    const int b  = blockIdx.z;        // 0..1
    const int tid = threadIdx.x;
    const int wv = tid >> 6, l = tid & 63;
    const int lhi = l >> 4, dj = l & 15;
    const int i0 = it * 16, j0 = jt * 16;

    __shared__ char smem[SMEMB];

    // ---- integer staged-cell bounds
    const int r0 = i0 / 6;
    const int i15 = i0 + 15, ci15 = i15 / 6;
    const int r1 = min(ci15 + ((i15 - 6 * ci15) == 5 ? 1 : 0), 63);
    const int c0 = j0 / 6;
    const int j15 = j0 + 15, cj15 = j15 / 6;
    const int c1 = min(cj15 + ((j15 - 6 * cj15) == 5 ? 1 : 0), 63);
    const int ncc = c1 - c0 + 1;              // 3 or 4
    const int ncell = (r1 - r0 + 1) * ncc;    // <= 16

    // ---- stage: cells (one b128 per thread), uv, W2F (2 b128 per thread)
    if (tid < (ncell << 5)) {
        int cl = tid >> 5, c16 = tid & 31;
        int cr = (ncc == 4) ? (cl >> 2) : ((cl * 11) >> 5);
        int cc = cl - cr * ncc;
        const _Float16* src = G + (((size_t)((b << 12) + ((r0 + cr) << 6) + (c0 + cc))) << 8) + (c16 << 3);
        *(f32x4*)(smem + cl * CELLB + (c16 << 4)) = *(const f32x4*)src;
    }
    if (tid < 64)
        *(f32x4*)(smem + UVB + (tid << 4)) = *(const f32x4*)(UVH + (tid << 3));
    {
        const f32x4* w2g = (const f32x4*)W2F;
#pragma unroll
        for (int t = 0; t < 4; ++t)
            *(f32x4*)(smem + W2B + ((t * 512 + tid) << 4)) = w2g[t * 512 + tid];
    }
    float bbv[4];
#pragma unroll
    for (int ng = 0; ng < 4; ++ng) bbv[ng] = b2[(ng << 4) + dj];
    __syncthreads();

    // ---- x setup (per lane)
    const int j = j0 + dj;
    const int cj = j / 6, pj = j - 6 * cj;
    const bool xs = (pj == 5) && (cj < 63);
    const float rx0 = (float)(2 * pj - 5) * (1.f / 6.f);
    const float rx1 = xs ? rx0 - 2.f : rx0;

    // ---- y setup: strip A = row ia (even => pia in {0,2,4}), strip B = ia+1
    const int ia = i0 + (wv << 1);
    const int cia = ia / 6, pia = ia - 6 * cia;
    const float ryA = (float)(2 * pia - 5) * (1.f / 6.f);
    const float ryB = ryA + (1.f / 3.f);
    const bool ysB = (pia == 4) && (cia < 63);
    const float ryB1 = ysB ? ryB - 2.f : ryB;

    // strip A weights (ys=false folded)
    const float aA0 = fabsf(ryA * rx0) + 1e-9f;
    const float aA1 = fabsf(ryA * rx1) + 1e-9f;
    const float invA = 1.f / (aA0 + aA1);
    const float W00A = xs ? aA1 * invA : 1.f;
    const float W01A = xs ? aA0 * invA : 0.f;
    // strip B weights (general, diagonal swap)
    const float aB0 = fabsf(ryB * rx0) + 1e-9f;
    const float aB1 = fabsf(ryB * rx1) + 1e-9f;
    const float aB2 = fabsf(ryB1 * rx0) + 1e-9f;
    const float aB3 = fabsf(ryB1 * rx1) + 1e-9f;
    const float invB = 1.f / (aB0 + aB1 + aB2 + aB3);
    float W00B = aB3, W01B = 0.f, W10B = 0.f, W11B = 0.f;
    if (xs) W01B += aB2; else W00B += aB2;
    if (ysB) W10B += aB1; else W00B += aB1;
    if (ysB && xs) W11B += aB0;
    else if (ysB)  W10B += aB0;
    else if (xs)   W01B += aB0;
    else           W00B += aB0;
    W00B *= invB; W01B *= invB; W10B *= invB; W11B *= invB;

#define DUP2(x) (f16x2){(_Float16)(x), (_Float16)(x)}
    const f16x2 ryAh = DUP2(ryA), ryB1h = DUP2(ryB1);
    const f16x2 rx0h = DUP2(rx0), rx1h = DUP2(rx1);
    const f16x2 thirdh = DUP2(1.f / 3.f);
    const f16x2 W00Ah = DUP2(W00A), W01Ah = DUP2(W01A);
    const f16x2 W00Bh = DUP2(W00B), W01Bh = DUP2(W01B);
    const f16x2 W10h = DUP2(W10B), W11h = DUP2(W11B);
    const f16x2 zeroh = DUP2(0.f);

    const int lo16 = lhi << 4;
    const int rA = cia - r0;
    const int cm = cj - c0, cp = cm + (xs ? 1 : 0);
    const char* cell00 = smem + (rA * ncc + cm) * CELLB + lo16;
    const char* cell01 = smem + (rA * ncc + cp) * CELLB + lo16;
    const char* cell10 = cell00 + ncc * CELLB;
    const char* cell11 = cell01 + ncc * CELLB;
    const char* uvp = smem + UVB + lo16;
    const f16x8* w2l = (const f16x8*)(smem + W2B) + l;

    f32x4 acc[2][4];
#pragma unroll
    for (int s = 0; s < 2; ++s)
#pragma unroll
        for (int ng = 0; ng < 4; ++ng) acc[s][ng] = (f32x4){0.f, 0.f, 0.f, 0.f};

#pragma unroll
    for (int ks = 0; ks < 8; ++ks) {
        const int ko = ks * 64;
        f16x8 uraw = *(const f16x8*)(uvp + ko);
        f16x8 vraw = *(const f16x8*)(uvp + 512 + ko);
        const f16x2* uu = (const f16x2*)&uraw;
        const f16x2* vv = (const f16x2*)&vraw;
        f16x8 bfr[4];
#pragma unroll
        for (int ng = 0; ng < 4; ++ng) bfr[ng] = w2l[(ks * 4 + ng) * 64];
        f16x8 gv00 = *(const f16x8*)(cell00 + ko);
        f16x8 gv01 = *(const f16x8*)(cell01 + ko);
        const f16x2* g00 = (const f16x2*)&gv00;
        const f16x2* g01 = (const f16x2*)&gv01;
        f16x2 hA[4], hB[4];
#pragma unroll
        for (int e = 0; e < 4; ++e) {
            f16x2 t00 = g00[e] + ryAh * uu[e] + rx0h * vv[e];
            f16x2 t01 = g01[e] + ryAh * uu[e] + rx1h * vv[e];
            f16x2 t00B = t00 + thirdh * uu[e];      // strip B shares cells, ry+1/3
            f16x2 t01B = t01 + thirdh * uu[e];
            t00 = __builtin_elementwise_max(t00, zeroh);
            t01 = __builtin_elementwise_max(t01, zeroh);
            t00B = __builtin_elementwise_max(t00B, zeroh);
            t01B = __builtin_elementwise_max(t01B, zeroh);
            hA[e] = W00Ah * t00 + W01Ah * t01;
            hB[e] = W00Bh * t00B + W01Bh * t01B;
        }
        if (ysB) {                                   // wave-uniform
            f16x8 gv10 = *(const f16x8*)(cell10 + ko);
            f16x8 gv11 = *(const f16x8*)(cell11 + ko);
            const f16x2* g10 = (const f16x2*)&gv10;
            const f16x2* g11 = (const f16x2*)&gv11;
#pragma unroll
            for (int e = 0; e < 4; ++e) {
                f16x2 t10 = g10[e] + ryB1h * uu[e] + rx0h * vv[e];
                f16x2 t11 = g11[e] + ryB1h * uu[e] + rx1h * vv[e];
                hB[e] += W10h * __builtin_elementwise_max(t10, zeroh);
                hB[e] += W11h * __builtin_elementwise_max(t11, zeroh);
            }
        }
        f16x8 afA, afB;
#pragma unroll
        for (int e = 0; e < 4; ++e) {
            afA[2 * e] = hA[e][0]; afA[2 * e + 1] = hA[e][1];
            afB[2 * e] = hB[e][0]; afB[2 * e + 1] = hB[e][1];
        }
#pragma unroll
        for (int ng = 0; ng < 4; ++ng)
            acc[0][ng] = __builtin_amdgcn_mfma_f32_16x16x32_f16(afA, bfr[ng], acc[0][ng], 0, 0, 0);
#pragma unroll
        for (int ng = 0; ng < 4; ++ng)
            acc[1][ng] = __builtin_amdgcn_mfma_f32_16x16x32_f16(afB, bfr[ng], acc[1][ng], 0, 0, 0);
    }

    // ---- epilogue: direct stores (D row = px col j0+lhi*4+r, D col = channel)
#pragma unroll
    for (int s = 0; s < 2; ++s) {
        const int irow = ia + s;
#pragma unroll
        for (int ng = 0; ng < 4; ++ng) {
            const int o = (ng << 4) + dj;
            float* op = out + (((size_t)b * NOUT + o) * HOUT + irow) * HOUT + j0 + (lhi << 2);
#pragma unroll
            for (int r = 0; r < 4; ++r)
                op[r] = acc[s][ng][r] + bbv[ng];
        }
    }
}

extern "C" void kernel_launch(void* const* d_in, const int* in_sizes, int n_in,
                              void* d_out, int out_size, void* d_ws, size_t ws_size,
                              hipStream_t stream) {
    const float* res = (const float*)d_in[0];
    const float* w1  = (const float*)d_in[1];
    const float* b1  = (const float*)d_in[2];
    const float* w2  = (const float*)d_in[3];
    const float* b2  = (const float*)d_in[4];
    float* out = (float*)d_out;

    char* ws = (char*)d_ws;
    _Float16* G   = (_Float16*)ws;                              // 4 MB
    _Float16* W2F = (_Float16*)(ws + (size_t)(8u << 20));       // 32 KB
    _Float16* W1F = (_Float16*)(ws + (size_t)(8u << 20) + 65536);
    _Float16* UVH = (_Float16*)(ws + (size_t)(8u << 20) + 131072);

    k_prep<<<130, 256, 0, stream>>>(w1, w2, W2F, W1F, UVH);
    k_gfeat<<<256, 256, 0, stream>>>(res, W1F, b1, G);
    k_main<<<dim3(24, 24, 2), 512, 0, stream>>>(G, W2F, UVH, b2, out);
}

// Round 13
// 39.975 us; speedup vs baseline: 2.0356x; 1.0164x over previous
//
#include <hip/hip_runtime.h>
#include <hip/hip_bf16.h>

typedef float f32x4 __attribute__((ext_vector_type(4)));
typedef _Float16 f16x2 __attribute__((ext_vector_type(2)));
typedef _Float16 f16x8 __attribute__((ext_vector_type(8)));

#define CC   64
#define HID  256
#define NOUT 64
#define HOUT 384
#define MAXCELL 16                // 16x16 tile: <=4 cell-rows x 4 cell-cols
#define CELLB 544                 // 512 data + 32 pad
#define UVB  (MAXCELL * CELLB)    // 8704
#define W2B  (UVB + 1024)         // 9728
#define SMEMB (W2B + 32768)       // 42496 B -> 3 blocks/CU (512 thr = 24 waves/CU)

// ---- k_prep: w2 -> W2F frags, w1[0:64] -> W1F frags, w1[64:66] -> UVH f16
__global__ __launch_bounds__(256) void k_prep(const float* __restrict__ w1,
                                              const float* __restrict__ w2,
                                              _Float16* __restrict__ W2F,
                                              _Float16* __restrict__ W1F,
                                              _Float16* __restrict__ UVH) {
    int idx = blockIdx.x * 256 + threadIdx.x;
    if (idx < 16384) {
        int f = idx, e = f & 7, l = (f >> 3) & 63, grp = f >> 9;
        int ks = grp >> 2, ng = grp & 3;
        int k = ks * 32 + ((l >> 4) << 3) + e;
        int n = (ng << 4) + (l & 15);
        W2F[f] = (_Float16)w2[k * NOUT + n];
    } else if (idx < 32768) {
        int f = idx - 16384, e = f & 7, l = (f >> 3) & 63, grp = f >> 9;
        int ks = grp >> 4, ng = grp & 15;
        int k = ks * 32 + ((l >> 4) << 3) + e;
        int n = (ng << 4) + (l & 15);
        W1F[f] = (_Float16)w1[k * HID + n];
    } else if (idx < 32768 + 512) {
        int f = idx - 32768;
        UVH[f] = (_Float16)w1[(CC + (f >> 8)) * HID + (f & 255)];
    }
}

// ---- k_gfeat (MFMA): G[cell][n] = b1[n] + sum_c res_f16[cell][c] * w1_f16[c][n]
__global__ __launch_bounds__(256) void k_gfeat(const float* __restrict__ res,
                                               const _Float16* __restrict__ W1F,
                                               const float* __restrict__ b1,
                                               _Float16* __restrict__ G) {
    const int cell0 = blockIdx.x * 32;
    const int b = cell0 >> 12, iyix0 = cell0 & 4095;
    const int tid = threadIdx.x;
    __shared__ _Float16 lds_a[32][72];
    __shared__ _Float16 lds_d[32][264];
    {
        int c = tid >> 2, cs = (tid & 3) * 8;
        const float* src = res + (((b * CC + c) << 12) + iyix0 + cs);
        f32x4 r0 = *(const f32x4*)src;
        f32x4 r1 = *(const f32x4*)(src + 4);
#pragma unroll
        for (int e = 0; e < 4; ++e) lds_a[cs + e][c] = (_Float16)r0[e];
#pragma unroll
        for (int e = 0; e < 4; ++e) lds_a[cs + 4 + e][c] = (_Float16)r1[e];
    }
    __syncthreads();
    const int wv = tid >> 6, l = tid & 63, lhi = l >> 4, dj = l & 15;
    const int crow = (wv & 1) * 16;
    const int nh = (wv >> 1) * 8;
    f32x4 acc[8];
#pragma unroll
    for (int q = 0; q < 8; ++q) {
        float bb = b1[(nh + q) * 16 + dj];
        acc[q] = (f32x4){bb, bb, bb, bb};
    }
#pragma unroll
    for (int ks = 0; ks < 2; ++ks) {
        f16x8 afr = *(const f16x8*)&lds_a[crow + dj][ks * 32 + lhi * 8];
#pragma unroll
        for (int q = 0; q < 8; ++q) {
            f16x8 bfr = *(const f16x8*)(W1F + (((ks * 16 + nh + q) * 64 + l) << 3));
            acc[q] = __builtin_amdgcn_mfma_f32_16x16x32_f16(afr, bfr, acc[q], 0, 0, 0);
        }
    }
#pragma unroll
    for (int q = 0; q < 8; ++q) {
        int n = (nh + q) * 16 + dj;
#pragma unroll
        for (int r = 0; r < 4; ++r)
            lds_d[crow + lhi * 4 + r][n] = (_Float16)acc[q][r];
    }
    __syncthreads();
    {
        int cell = tid >> 3, ch = (tid & 7) * 32;
        _Float16* dst = G + (((size_t)(cell0 + cell)) << 8) + ch;
#pragma unroll
        for (int r = 0; r < 4; ++r)
            *(f32x4*)(dst + r * 8) = *(const f32x4*)&lds_d[cell][ch + r * 8];
    }
}

// ---- main: block = 8 waves (512 thr), tile = 16 rows x 16 cols; wave = 2
// adjacent rows sharing one cell-row (strip A even => never splits). ks-outer:
// uv + w2 read once per ks for 32 px; W2F staged once per 512-thread block.
// NOTE: launch_bounds min-waves arg = 2 (NOT 6): at 8 waves/block the arg is
// effectively multiplied by waves/block in the VGPR-cap calc; 6 forced a
// 40-VGPR spill-storm (R11: +131 MB scratch writes).
__global__ __launch_bounds__(512, 2) void k_main(const _Float16* __restrict__ G,
                                                 const _Float16* __restrict__ W2F,
                                                 const _Float16* __restrict__ UVH,
                                                 const float* __restrict__ b2,
                                                 float* __restrict__ out) {
    const int jt = blockIdx.x;        // 0..23
    const int it = blockIdx.y;        // 0..23
    const int b  = blockIdx.z;        // 0..1
    const int tid = threadIdx.x;
    const int wv = tid >> 6, l = tid & 63;
    const int lhi = l >> 4, dj = l & 15;
    const int i0 = it * 16, j0 = jt * 16;

    __shared__ char smem[SMEMB];

    // ---- integer staged-cell bounds
    const int r0 = i0 / 6;
    const int i15 = i0 + 15, ci15 = i15 / 6;
    const int r1 = min(ci15 + ((i15 - 6 * ci15) == 5 ? 1 : 0), 63);
    const int c0 = j0 / 6;
    const int j15 = j0 + 15, cj15 = j15 / 6;
    const int c1 = min(cj15 + ((j15 - 6 * cj15) == 5 ? 1 : 0), 63);
    const int ncc = c1 - c0 + 1;              // 3 or 4
    const int ncell = (r1 - r0 + 1) * ncc;    // <= 16

    // ---- stage: cells (one b128 per thread), uv, W2F (2 b128 per thread)
    if (tid < (ncell << 5)) {
        int cl = tid >> 5, c16 = tid & 31;
        int cr = (ncc == 4) ? (cl >> 2) : ((cl * 11) >> 5);
        int cc = cl - cr * ncc;
        const _Float16* src = G + (((size_t)((b << 12) + ((r0 + cr) << 6) + (c0 + cc))) << 8) + (c16 << 3);
        *(f32x4*)(smem + cl * CELLB + (c16 << 4)) = *(const f32x4*)src;
    }
    if (tid < 64)
        *(f32x4*)(smem + UVB + (tid << 4)) = *(const f32x4*)(UVH + (tid << 3));
    {
        const f32x4* w2g = (const f32x4*)W2F;
#pragma unroll
        for (int t = 0; t < 4; ++t)
            *(f32x4*)(smem + W2B + ((t * 512 + tid) << 4)) = w2g[t * 512 + tid];
    }
    float bbv[4];
#pragma unroll
    for (int ng = 0; ng < 4; ++ng) bbv[ng] = b2[(ng << 4) + dj];
    __syncthreads();

    // ---- x setup (per lane)
    const int j = j0 + dj;
    const int cj = j / 6, pj = j - 6 * cj;
    const bool xs = (pj == 5) && (cj < 63);
    const float rx0 = (float)(2 * pj - 5) * (1.f / 6.f);
    const float rx1 = xs ? rx0 - 2.f : rx0;

    // ---- y setup: strip A = row ia (even => pia in {0,2,4}), strip B = ia+1
    const int ia = i0 + (wv << 1);
    const int cia = ia / 6, pia = ia - 6 * cia;
    const float ryA = (float)(2 * pia - 5) * (1.f / 6.f);
    const float ryB = ryA + (1.f / 3.f);
    const bool ysB = (pia == 4) && (cia < 63);
    const float ryB1 = ysB ? ryB - 2.f : ryB;

    // strip A weights (ys=false folded)
    const float aA0 = fabsf(ryA * rx0) + 1e-9f;
    const float aA1 = fabsf(ryA * rx1) + 1e-9f;
    const float invA = 1.f / (aA0 + aA1);
    const float W00A = xs ? aA1 * invA : 1.f;
    const float W01A = xs ? aA0 * invA : 0.f;
    // strip B weights (general, diagonal swap)
    const float aB0 = fabsf(ryB * rx0) + 1e-9f;
    const float aB1 = fabsf(ryB * rx1) + 1e-9f;
    const float aB2 = fabsf(ryB1 * rx0) + 1e-9f;
    const float aB3 = fabsf(ryB1 * rx1) + 1e-9f;
    const float invB = 1.f / (aB0 + aB1 + aB2 + aB3);
    float W00B = aB3, W01B = 0.f, W10B = 0.f, W11B = 0.f;
    if (xs) W01B += aB2; else W00B += aB2;
    if (ysB) W10B += aB1; else W00B += aB1;
    if (ysB && xs) W11B += aB0;
    else if (ysB)  W10B += aB0;
    else if (xs)   W01B += aB0;
    else           W00B += aB0;
    W00B *= invB; W01B *= invB; W10B *= invB; W11B *= invB;

#define DUP2(x) (f16x2){(_Float16)(x), (_Float16)(x)}
    const f16x2 ryAh = DUP2(ryA), ryB1h = DUP2(ryB1);
    const f16x2 rx0h = DUP2(rx0), rx1h = DUP2(rx1);
    const f16x2 thirdh = DUP2(1.f / 3.f);
    const f16x2 W00Ah = DUP2(W00A), W01Ah = DUP2(W01A);
    const f16x2 W00Bh = DUP2(W00B), W01Bh = DUP2(W01B);
    const f16x2 W10h = DUP2(W10B), W11h = DUP2(W11B);
    const f16x2 zeroh = DUP2(0.f);

    const int lo16 = lhi << 4;
    const int rA = cia - r0;
    const int cm = cj - c0, cp = cm + (xs ? 1 : 0);
    const char* cell00 = smem + (rA * ncc + cm) * CELLB + lo16;
    const char* cell01 = smem + (rA * ncc + cp) * CELLB + lo16;
    const char* cell10 = cell00 + ncc * CELLB;
    const char* cell11 = cell01 + ncc * CELLB;
    const char* uvp = smem + UVB + lo16;
    const f16x8* w2l = (const f16x8*)(smem + W2B) + l;

    f32x4 acc[2][4];
#pragma unroll
    for (int s = 0; s < 2; ++s)
#pragma unroll
        for (int ng = 0; ng < 4; ++ng) acc[s][ng] = (f32x4){0.f, 0.f, 0.f, 0.f};

#pragma unroll
    for (int ks = 0; ks < 8; ++ks) {
        const int ko = ks * 64;
        f16x8 uraw = *(const f16x8*)(uvp + ko);
        f16x8 vraw = *(const f16x8*)(uvp + 512 + ko);
        const f16x2* uu = (const f16x2*)&uraw;
        const f16x2* vv = (const f16x2*)&vraw;
        f16x8 bfr[4];
#pragma unroll
        for (int ng = 0; ng < 4; ++ng) bfr[ng] = w2l[(ks * 4 + ng) * 64];
        f16x8 gv00 = *(const f16x8*)(cell00 + ko);
        f16x8 gv01 = *(const f16x8*)(cell01 + ko);
        const f16x2* g00 = (const f16x2*)&gv00;
        const f16x2* g01 = (const f16x2*)&gv01;
        f16x2 hA[4], hB[4];
#pragma unroll
        for (int e = 0; e < 4; ++e) {
            f16x2 t00 = g00[e] + ryAh * uu[e] + rx0h * vv[e];
            f16x2 t01 = g01[e] + ryAh * uu[e] + rx1h * vv[e];
            f16x2 t00B = t00 + thirdh * uu[e];      // strip B shares cells, ry+1/3
            f16x2 t01B = t01 + thirdh * uu[e];
            t00 = __builtin_elementwise_max(t00, zeroh);
            t01 = __builtin_elementwise_max(t01, zeroh);
            t00B = __builtin_elementwise_max(t00B, zeroh);
            t01B = __builtin_elementwise_max(t01B, zeroh);
            hA[e] = W00Ah * t00 + W01Ah * t01;
            hB[e] = W00Bh * t00B + W01Bh * t01B;
        }
        if (ysB) {                                   // wave-uniform
            f16x8 gv10 = *(const f16x8*)(cell10 + ko);
            f16x8 gv11 = *(const f16x8*)(cell11 + ko);
            const f16x2* g10 = (const f16x2*)&gv10;
            const f16x2* g11 = (const f16x2*)&gv11;
#pragma unroll
            for (int e = 0; e < 4; ++e) {
                f16x2 t10 = g10[e] + ryB1h * uu[e] + rx0h * vv[e];
                f16x2 t11 = g11[e] + ryB1h * uu[e] + rx1h * vv[e];
                hB[e] += W10h * __builtin_elementwise_max(t10, zeroh);
                hB[e] += W11h * __builtin_elementwise_max(t11, zeroh);
            }
        }
        f16x8 afA, afB;
#pragma unroll
        for (int e = 0; e < 4; ++e) {
            afA[2 * e] = hA[e][0]; afA[2 * e + 1] = hA[e][1];
            afB[2 * e] = hB[e][0]; afB[2 * e + 1] = hB[e][1];
        }
#pragma unroll
        for (int ng = 0; ng < 4; ++ng)
            acc[0][ng] = __builtin_amdgcn_mfma_f32_16x16x32_f16(afA, bfr[ng], acc[0][ng], 0, 0, 0);
#pragma unroll
        for (int ng = 0; ng < 4; ++ng)
            acc[1][ng] = __builtin_amdgcn_mfma_f32_16x16x32_f16(afB, bfr[ng], acc[1][ng], 0, 0, 0);
    }

    // ---- epilogue: direct stores (D row = px col j0+lhi*4+r, D col = channel)
#pragma unroll
    for (int s = 0; s < 2; ++s) {
        const int irow = ia + s;
#pragma unroll
        for (int ng = 0; ng < 4; ++ng) {
            const int o = (ng << 4) + dj;
            float* op = out + (((size_t)b * NOUT + o) * HOUT + irow) * HOUT + j0 + (lhi << 2);
#pragma unroll
            for (int r = 0; r < 4; ++r)
                op[r] = acc[s][ng][r] + bbv[ng];
        }
    }
}

extern "C" void kernel_launch(void* const* d_in, const int* in_sizes, int n_in,
                              void* d_out, int out_size, void* d_ws, size_t ws_size,
                              hipStream_t stream) {
    const float* res = (const float*)d_in[0];
    const float* w1  = (const float*)d_in[1];
    const float* b1  = (const float*)d_in[2];
    const float* w2  = (const float*)d_in[3];
    const float* b2  = (const float*)d_in[4];
    float* out = (float*)d_out;

    char* ws = (char*)d_ws;
    _Float16* G   = (_Float16*)ws;                              // 4 MB
    _Float16* W2F = (_Float16*)(ws + (size_t)(8u << 20));       // 32 KB
    _Float16* W1F = (_Float16*)(ws + (size_t)(8u << 20) + 65536);
    _Float16* UVH = (_Float16*)(ws + (size_t)(8u << 20) + 131072);

    k_prep<<<130, 256, 0, stream>>>(w1, w2, W2F, W1F, UVH);
    k_gfeat<<<256, 256, 0, stream>>>(res, W1F, b1, G);
    k_main<<<dim3(24, 24, 2), 512, 0, stream>>>(G, W2F, UVH, b2, out);
}